// Round 21
// baseline (283.821 us; speedup 1.0000x reference)
//
#include <hip/hip_runtime.h>

typedef __bf16 bf16x8 __attribute__((ext_vector_type(8)));
typedef float f32x4 __attribute__((ext_vector_type(4)));
typedef float f32x16 __attribute__((ext_vector_type(16)));

#define MFMA16(a,b,c) __builtin_amdgcn_mfma_f32_16x16x32_bf16(a,b,c,0,0,0)
#define MFMA32(a,b,c) __builtin_amdgcn_mfma_f32_32x32x16_bf16(a,b,c,0,0,0)

__device__ __forceinline__ unsigned short f2bf(float f) {
  unsigned int u = __float_as_uint(f);
  u = (u + 0x7FFFu + ((u >> 16) & 1u)) >> 16;
  return (unsigned short)u;
}

__device__ __forceinline__ void gload16(const void* g, void* l) {
  __builtin_amdgcn_global_load_lds(
      (const __attribute__((address_space(1))) void*)g,
      (__attribute__((address_space(3))) void*)l, 16, 0, 0);
}

__device__ __forceinline__ float vexp2(float x) {
  float r;
  asm("v_exp_f32 %0, %1" : "=v"(r) : "v"(x));
  return r;
}

// Build PV B-fragment (B[k=key][n=q], k = hi*8 + j) from the 8 fp32 P values
// this lane holds for one 16-key group (C/D order: key = (r&3) + 8*(r>>2) + 4*hi).
__device__ __forceinline__ bf16x8 mk_pfrag(int hi, float p0, float p1, float p2, float p3,
                                           float p4, float p5, float p6, float p7) {
  unsigned int a0, a1, b0, b1;
  asm("v_cvt_pk_bf16_f32 %0, %1, %2" : "=v"(a0) : "v"(p0), "v"(p1));
  asm("v_cvt_pk_bf16_f32 %0, %1, %2" : "=v"(a1) : "v"(p2), "v"(p3));
  asm("v_cvt_pk_bf16_f32 %0, %1, %2" : "=v"(b0) : "v"(p4), "v"(p5));
  asm("v_cvt_pk_bf16_f32 %0, %1, %2" : "=v"(b1) : "v"(p6), "v"(p7));
  unsigned int x = __shfl_xor(hi ? a0 : b0, 32);
  unsigned int y = __shfl_xor(hi ? a1 : b1, 32);
  uint4 w;
  w.x = hi ? x : a0;
  w.y = hi ? y : a1;
  w.z = hi ? b0 : x;
  w.w = hi ? b1 : y;
  return *reinterpret_cast<bf16x8*>(&w);
}

// ---------------- convert x (fp32) -> bf16 ----------------
__global__ __launch_bounds__(256) void k_convx(const float* __restrict__ x,
                                               unsigned short* __restrict__ xb) {
  int i = (blockIdx.x * 256 + threadIdx.x) * 4;
  float4 v = *reinterpret_cast<const float4*>(x + i);
  ushort4 o;
  o.x = f2bf(v.x); o.y = f2bf(v.y); o.z = f2bf(v.z); o.w = f2bf(v.w);
  *reinterpret_cast<ushort4*>(xb + i) = o;
}

// ---------------- transpose-convert W (fp32 [1024][1024]) -> WT bf16 [N][K] ----------------
__global__ __launch_bounds__(256) void k_transw(const float* __restrict__ W,
                                                unsigned short* __restrict__ WT) {
  __shared__ float t[32][33];
  int bx = blockIdx.x * 32;
  int by = blockIdx.y * 32;
  int tx = threadIdx.x & 31;
  int ty = threadIdx.x >> 5;
#pragma unroll
  for (int i = 0; i < 32; i += 8)
    t[ty + i][tx] = W[(size_t)(by + ty + i) * 1024 + bx + tx];
  __syncthreads();
#pragma unroll
  for (int i = 0; i < 32; i += 8)
    WT[(size_t)(bx + ty + i) * 1024 + by + tx] = f2bf(t[tx][ty + i]);
}

// ---------------- GEMM 128x128, BK=64, swizzled LDS (R17 green) ----------------
template <int EPI>
__global__ __launch_bounds__(256) void k_gemm(
    const unsigned short* __restrict__ A, const unsigned short* __restrict__ BT, int K,
    unsigned short* __restrict__ Qf, unsigned short* __restrict__ Kf,
    unsigned short* __restrict__ VT, const float* __restrict__ alphaPtr,
    float* __restrict__ Out) {
  __shared__ __align__(16) unsigned short smem[128 * 136];
  unsigned short* As = smem;
  unsigned short* Bs = smem + 8192;
  const int tid = threadIdx.x;
  const int wave = tid >> 6, lane = tid & 63;
  const int l15 = lane & 15, lg = lane >> 4;
  const int l7 = l15 & 7;
  const int wr = wave >> 1, wc = wave & 1;
  const int bm = blockIdx.x, bn = blockIdx.y;

  f32x4 acc[4][4] = {};
  const unsigned short* Ab = A + (size_t)bm * 128 * K;
  const unsigned short* Bb = BT + (size_t)bn * 128 * K;

  const int srow = wave * 8 + (lane >> 3);
  const int scol = ((lane & 7) ^ (lane >> 3)) << 3;

  for (int k0 = 0; k0 < K; k0 += 64) {
#pragma unroll
    for (int c = 0; c < 4; ++c) {
      gload16((const void*)(Ab + (size_t)(32 * c + srow) * K + k0 + scol),
              (char*)As + c * 4096 + wave * 1024);
      gload16((const void*)(Bb + (size_t)(32 * c + srow) * K + k0 + scol),
              (char*)Bs + c * 4096 + wave * 1024);
    }
    __syncthreads();
#pragma unroll
    for (int kk = 0; kk < 2; ++kk) {
      bf16x8 af[4], bfr[4];
#pragma unroll
      for (int mi = 0; mi < 4; ++mi) {
        int R = wr * 64 + mi * 16 + l15;
        af[mi] = *reinterpret_cast<const bf16x8*>(&As[R * 64 + (((kk * 4 + lg)) ^ l7) * 8]);
      }
#pragma unroll
      for (int ni = 0; ni < 4; ++ni) {
        int R = wc * 64 + ni * 16 + l15;
        bfr[ni] = *reinterpret_cast<const bf16x8*>(&Bs[R * 64 + (((kk * 4 + lg)) ^ l7) * 8]);
      }
      __builtin_amdgcn_s_setprio(1);
#pragma unroll
      for (int mi = 0; mi < 4; ++mi)
#pragma unroll
        for (int ni = 0; ni < 4; ++ni)
          acc[mi][ni] = MFMA16(af[mi], bfr[ni], acc[mi][ni]);
      __builtin_amdgcn_s_setprio(0);
    }
    __syncthreads();
  }

  if (EPI == 0) {
    const float av = alphaPtr[0];
    const int t = bn >> 3;
    if (t == 2) {
#pragma unroll
      for (int mi = 0; mi < 4; ++mi) {
        int row0 = bm * 128 + wr * 64 + mi * 16 + lg * 4;
        int bb = row0 >> 11, s = row0 & 2047;
#pragma unroll
        for (int ni = 0; ni < 4; ++ni) {
          int col = (bn & 7) * 128 + wc * 64 + ni * 16 + l15;
          int hh = col >> 6, dd = col & 63;
          ushort4 pk;
#pragma unroll
          for (int r = 0; r < 4; ++r) {
            float v = acc[mi][ni][r];
            float e = __expf(2.0f * v);
            v += av * 0.1f * (1.0f - 2.0f * __builtin_amdgcn_rcpf(e + 1.0f));
            ((unsigned short*)&pk)[r] = f2bf(v);
          }
          *reinterpret_cast<ushort4*>(VT + ((size_t)(bb * 16 + hh) * 64 + dd) * 2048 + s) = pk;
        }
      }
    } else {
#pragma unroll
      for (int mi = 0; mi < 4; ++mi)
#pragma unroll
        for (int ni = 0; ni < 4; ++ni)
#pragma unroll
          for (int r = 0; r < 4; ++r) {
            int row = wr * 64 + mi * 16 + lg * 4 + r;
            int col = wc * 64 + ni * 16 + l15;
            float v = acc[mi][ni][r];
            if (t == 0) {
              v += 0.1f * __sinf(v);
              v *= 0.18033688011112042f;  // C1: fold softmax scale*log2e into Q
            } else {
              v += 0.1f * __cosf(v);
            }
            smem[row * 136 + col] = f2bf(v);
          }
      __syncthreads();
      unsigned short* dst = (t == 0) ? Qf : Kf;
      const int c16 = tid & 15, rb = tid >> 4;
      const int ncol0 = (bn & 7) * 128;
#pragma unroll
      for (int i2 = 0; i2 < 8; ++i2) {
        int srow2 = rb + i2 * 16;
        uint4 val = *reinterpret_cast<const uint4*>(&smem[srow2 * 136 + c16 * 8]);
        *reinterpret_cast<uint4*>(dst + (size_t)(bm * 128 + srow2) * 1024 + ncol0 + c16 * 8) = val;
      }
    }
  } else {
#pragma unroll
    for (int ni = 0; ni < 4; ++ni) {
      int n = bn * 128 + wc * 64 + ni * 16 + l15;
#pragma unroll
      for (int mi = 0; mi < 4; ++mi) {
        int row = bm * 128 + wr * 64 + mi * 16 + lg * 4;
#pragma unroll
        for (int r = 0; r < 4; ++r)
          Out[(size_t)(row + r) * 1024 + n] = acc[mi][ni][r];
      }
    }
  }
}

// ---------------- flash attention: K direct-from-L2, V via 2-buf LDS ------------
// K fragments read straight from global (panel is L2-resident; every 128B K-row
// line is fully consumed by the wave -> zero over-fetch). V stays LDS-staged with
// the R11-proven safe schedule: issue V(t+1) -> compute t -> __syncthreads().
// No hand-written vmcnt anywhere (compiler manages all waits).
__global__ __launch_bounds__(256)
void k_attn(const unsigned short* __restrict__ Qf,
            const unsigned short* __restrict__ Kf,
            const unsigned short* __restrict__ VT,
            unsigned short* __restrict__ AO) {
  __shared__ __align__(16) unsigned short smem[9216];  // V bufs 2x4096 elems | epilogue 4x2304
  const int tid = threadIdx.x;
  const int wave = tid >> 6, lane = tid & 63;
  const int l31 = lane & 31, hi = lane >> 5;
  const int f = (blockIdx.y << 4) | blockIdx.x;
  const int nf = ((f & 7) << 7) | (f >> 3);
  const int qb = nf & 15, bh = nf >> 4;
  const int b = bh >> 4, h = bh & 15;

  const unsigned short* Qb = Qf + ((size_t)b * 2048 + qb * 128 + wave * 32) * 1024 + h * 64;
  const unsigned short* Kb = Kf + (size_t)b * 2048 * 1024 + h * 64;
  const unsigned short* Vb = VT + (size_t)bh * 64 * 2048;

  bf16x8 qfr[4];
#pragma unroll
  for (int ds = 0; ds < 4; ++ds)
    qfr[ds] = *reinterpret_cast<const bf16x8*>(Qb + (size_t)l31 * 1024 + ds * 16 + hi * 8);

  float lsum = 0.f;
  f32x16 o0 = {}, o1 = {};

  // V staging map (identical to proven kernels): wave stages rows krow0, krow0+8
  const int krow0 = wave * 16 + (lane >> 3);
  const int ksrcc = ((lane & 7) ^ (lane >> 3)) << 3;  // pre-swizzled source chunk
  const int kxor = l31 & 7;                           // read-side chunk XOR (V only)

  // ---- prologue: stage V tile 0 into buffer 0 ----
  {
    char* Vd = (char*)smem + wave * 2048;
    gload16((const void*)(Vb + (size_t)krow0 * 2048 + ksrcc), Vd);
    gload16((const void*)(Vb + (size_t)(krow0 + 8) * 2048 + ksrcc), Vd + 1024);
  }
  __syncthreads();

  for (int t = 0; t < 32; ++t) {
    const unsigned short* VTC = smem + (t & 1) * 4096;
    const unsigned short* Kp = Kb + (size_t)t * 64 * 1024;  // K tile base (rows t*64..)

    // ---- issue V tile t+1 into the other buffer (freed by previous sync) ----
    if (t < 31) {
      int kn = (t + 1) * 64;
      char* Vd = (char*)(smem + ((t + 1) & 1) * 4096) + wave * 2048;
      gload16((const void*)(Vb + (size_t)krow0 * 2048 + kn + ksrcc), Vd);
      gload16((const void*)(Vb + (size_t)(krow0 + 8) * 2048 + kn + ksrcc), Vd + 1024);
    }

    // ---- QK^T swapped: S^T[key][q] = MFMA(A=K direct, B=Q') ----
    f32x16 s0 = {}, s1 = {};
    __builtin_amdgcn_s_setprio(1);
#pragma unroll
    for (int ds = 0; ds < 4; ++ds) {
      bf16x8 kf0 = *reinterpret_cast<const bf16x8*>(Kp + (size_t)l31 * 1024 + ds * 16 + hi * 8);
      bf16x8 kf1 = *reinterpret_cast<const bf16x8*>(Kp + (size_t)(l31 + 32) * 1024 + ds * 16 + hi * 8);
      s0 = MFMA32(kf0, qfr[ds], s0);
      s1 = MFMA32(kf1, qfr[ds], s1);
    }
    __builtin_amdgcn_s_setprio(0);

    // ---- fixed-max softmax: p = 2^s (C1 pre-folded into Q); lane-local lsum ----
    float rs0 = 0.f, rs1 = 0.f, rs2 = 0.f, rs3 = 0.f;
#pragma unroll
    for (int r = 0; r < 16; r += 4) {
      float p0 = vexp2(s0[r]);     s0[r] = p0;     rs0 += p0;
      float p1 = vexp2(s0[r + 1]); s0[r + 1] = p1; rs1 += p1;
      float p2 = vexp2(s0[r + 2]); s0[r + 2] = p2; rs2 += p2;
      float p3 = vexp2(s0[r + 3]); s0[r + 3] = p3; rs3 += p3;
    }
#pragma unroll
    for (int r = 0; r < 16; r += 4) {
      float p0 = vexp2(s1[r]);     s1[r] = p0;     rs0 += p0;
      float p1 = vexp2(s1[r + 1]); s1[r + 1] = p1; rs1 += p1;
      float p2 = vexp2(s1[r + 2]); s1[r + 2] = p2; rs2 += p2;
      float p3 = vexp2(s1[r + 3]); s1[r + 3] = p3; rs3 += p3;
    }
    lsum += (rs0 + rs1) + (rs2 + rs3);

    // ---- PV swapped: out^T[d][q] += MFMA(A=V^T from LDS, B=P) ----
    __builtin_amdgcn_s_setprio(1);
#pragma unroll
    for (int ks = 0; ks < 4; ++ks) {
      bf16x8 pf =
          (ks == 0) ? mk_pfrag(hi, s0[0], s0[1], s0[2], s0[3], s0[4], s0[5], s0[6], s0[7])
        : (ks == 1) ? mk_pfrag(hi, s0[8], s0[9], s0[10], s0[11], s0[12], s0[13], s0[14], s0[15])
        : (ks == 2) ? mk_pfrag(hi, s1[0], s1[1], s1[2], s1[3], s1[4], s1[5], s1[6], s1[7])
                    : mk_pfrag(hi, s1[8], s1[9], s1[10], s1[11], s1[12], s1[13], s1[14], s1[15]);
      int ch = ((ks * 2 + hi) ^ kxor) * 8;
      bf16x8 v0 = *reinterpret_cast<const bf16x8*>(&VTC[l31 * 64 + ch]);
      bf16x8 v1 = *reinterpret_cast<const bf16x8*>(&VTC[(l31 + 32) * 64 + ch]);
      o0 = MFMA32(v0, pf, o0);
      o1 = MFMA32(v1, pf, o1);
    }
    __builtin_amdgcn_s_setprio(0);
    __syncthreads();  // full drain: V(t+1) staged; all waves done reading VTC
  }

  // ---- epilogue: single cross-lane lsum reduce, normalize, store via LDS ----
  lsum += __shfl_xor(lsum, 32);
  const float inv = 1.0f / lsum;
  unsigned short* OL = smem + wave * 2304;
#pragma unroll
  for (int r = 0; r < 16; ++r) {
    int d0 = (r & 3) + 8 * (r >> 2) + 4 * hi;
    OL[l31 * 72 + d0] = f2bf(o0[r] * inv);
    OL[l31 * 72 + 32 + d0] = f2bf(o1[r] * inv);
  }
  __syncthreads();
#pragma unroll
  for (int p = 0; p < 4; ++p) {
    int u = tid + p * 256;
    int row = u >> 3, ch = u & 7;
    uint4 val = *reinterpret_cast<const uint4*>(&smem[(row >> 5) * 2304 + (row & 31) * 72 + ch * 8]);
    *reinterpret_cast<uint4*>(AO + ((size_t)b * 2048 + qb * 128 + row) * 1024 + h * 64 + ch * 8) = val;
  }
}

extern "C" void kernel_launch(void* const* d_in, const int* in_sizes, int n_in,
                              void* d_out, int out_size, void* d_ws, size_t ws_size,
                              hipStream_t stream) {
  const float* x = (const float*)d_in[0];
  const float* Wq = (const float*)d_in[1];
  const float* Wk = (const float*)d_in[2];
  const float* Wv = (const float*)d_in[3];
  const float* Wo = (const float*)d_in[4];
  const float* alpha = (const float*)d_in[5];
  float* out = (float*)d_out;

  char* ws = (char*)d_ws;
  unsigned short* xb  = (unsigned short*)(ws);
  unsigned short* WT3 = (unsigned short*)(ws + 16777216);
  unsigned short* WoT = (unsigned short*)(ws + 23068672);
  unsigned short* Qf  = (unsigned short*)(ws + 25165824);
  unsigned short* Kf  = (unsigned short*)(ws + 41943040);
  unsigned short* VTb = (unsigned short*)(ws + 58720256);  // [B][H][64][2048]
  unsigned short* AO  = (unsigned short*)(ws + 75497472);

  k_convx<<<dim3(8192), dim3(256), 0, stream>>>(x, xb);
  k_transw<<<dim3(32, 32), dim3(256), 0, stream>>>(Wq, WT3);
  k_transw<<<dim3(32, 32), dim3(256), 0, stream>>>(Wk, WT3 + 1024 * 1024);
  k_transw<<<dim3(32, 32), dim3(256), 0, stream>>>(Wv, WT3 + 2 * 1024 * 1024);
  k_transw<<<dim3(32, 32), dim3(256), 0, stream>>>(Wo, WoT);

  k_gemm<0><<<dim3(64, 24), dim3(256), 0, stream>>>(xb, WT3, 1024, Qf, Kf, VTb, alpha, nullptr);
  k_attn<<<dim3(16, 64), dim3(256), 0, stream>>>(Qf, Kf, VTb, AO);
  k_gemm<1><<<dim3(64, 8), dim3(256), 0, stream>>>(AO, WoT, 1024, nullptr, nullptr, nullptr, nullptr, out);
}

// Round 22
// 220.310 us; speedup vs baseline: 1.2883x; 1.2883x over previous
//
#include <hip/hip_runtime.h>

typedef __bf16 bf16x8 __attribute__((ext_vector_type(8)));
typedef float f32x4 __attribute__((ext_vector_type(4)));
typedef float f32x16 __attribute__((ext_vector_type(16)));

#define MFMA16(a,b,c) __builtin_amdgcn_mfma_f32_16x16x32_bf16(a,b,c,0,0,0)
#define MFMA32(a,b,c) __builtin_amdgcn_mfma_f32_32x32x16_bf16(a,b,c,0,0,0)

__device__ __forceinline__ unsigned short f2bf(float f) {
  unsigned int u = __float_as_uint(f);
  u = (u + 0x7FFFu + ((u >> 16) & 1u)) >> 16;
  return (unsigned short)u;
}

__device__ __forceinline__ void gload16(const void* g, void* l) {
  __builtin_amdgcn_global_load_lds(
      (const __attribute__((address_space(1))) void*)g,
      (__attribute__((address_space(3))) void*)l, 16, 0, 0);
}

__device__ __forceinline__ float vexp2(float x) {
  float r;
  asm("v_exp_f32 %0, %1" : "=v"(r) : "v"(x));
  return r;
}

// Build PV B-fragment (B[k=key][n=q], k = hi*8 + j) from the 8 fp32 P values
// this lane holds for one 16-key group (C/D order: key = (r&3) + 8*(r>>2) + 4*hi).
__device__ __forceinline__ bf16x8 mk_pfrag(int hi, float p0, float p1, float p2, float p3,
                                           float p4, float p5, float p6, float p7) {
  unsigned int a0, a1, b0, b1;
  asm("v_cvt_pk_bf16_f32 %0, %1, %2" : "=v"(a0) : "v"(p0), "v"(p1));
  asm("v_cvt_pk_bf16_f32 %0, %1, %2" : "=v"(a1) : "v"(p2), "v"(p3));
  asm("v_cvt_pk_bf16_f32 %0, %1, %2" : "=v"(b0) : "v"(p4), "v"(p5));
  asm("v_cvt_pk_bf16_f32 %0, %1, %2" : "=v"(b1) : "v"(p6), "v"(p7));
  unsigned int x = __shfl_xor(hi ? a0 : b0, 32);
  unsigned int y = __shfl_xor(hi ? a1 : b1, 32);
  uint4 w;
  w.x = hi ? x : a0;
  w.y = hi ? y : a1;
  w.z = hi ? b0 : x;
  w.w = hi ? b1 : y;
  return *reinterpret_cast<bf16x8*>(&w);
}

// ---------------- convert x (fp32) -> bf16 ----------------
__global__ __launch_bounds__(256) void k_convx(const float* __restrict__ x,
                                               unsigned short* __restrict__ xb) {
  int i = (blockIdx.x * 256 + threadIdx.x) * 4;
  float4 v = *reinterpret_cast<const float4*>(x + i);
  ushort4 o;
  o.x = f2bf(v.x); o.y = f2bf(v.y); o.z = f2bf(v.z); o.w = f2bf(v.w);
  *reinterpret_cast<ushort4*>(xb + i) = o;
}

// ---------------- transpose-convert W (fp32 [1024][1024]) -> WT bf16 [N][K] ----------------
__global__ __launch_bounds__(256) void k_transw(const float* __restrict__ W,
                                                unsigned short* __restrict__ WT) {
  __shared__ float t[32][33];
  int bx = blockIdx.x * 32;
  int by = blockIdx.y * 32;
  int tx = threadIdx.x & 31;
  int ty = threadIdx.x >> 5;
#pragma unroll
  for (int i = 0; i < 32; i += 8)
    t[ty + i][tx] = W[(size_t)(by + ty + i) * 1024 + bx + tx];
  __syncthreads();
#pragma unroll
  for (int i = 0; i < 32; i += 8)
    WT[(size_t)(bx + ty + i) * 1024 + by + tx] = f2bf(t[tx][ty + i]);
}

// ---------------- GEMM 128x128, BK=64, swizzled LDS (R17 green) ----------------
template <int EPI>
__global__ __launch_bounds__(256) void k_gemm(
    const unsigned short* __restrict__ A, const unsigned short* __restrict__ BT, int K,
    unsigned short* __restrict__ Qf, unsigned short* __restrict__ Kf,
    unsigned short* __restrict__ VT, const float* __restrict__ alphaPtr,
    float* __restrict__ Out) {
  __shared__ __align__(16) unsigned short smem[128 * 136];
  unsigned short* As = smem;
  unsigned short* Bs = smem + 8192;
  const int tid = threadIdx.x;
  const int wave = tid >> 6, lane = tid & 63;
  const int l15 = lane & 15, lg = lane >> 4;
  const int l7 = l15 & 7;
  const int wr = wave >> 1, wc = wave & 1;
  const int bm = blockIdx.x, bn = blockIdx.y;

  f32x4 acc[4][4] = {};
  const unsigned short* Ab = A + (size_t)bm * 128 * K;
  const unsigned short* Bb = BT + (size_t)bn * 128 * K;

  const int srow = wave * 8 + (lane >> 3);
  const int scol = ((lane & 7) ^ (lane >> 3)) << 3;

  for (int k0 = 0; k0 < K; k0 += 64) {
#pragma unroll
    for (int c = 0; c < 4; ++c) {
      gload16((const void*)(Ab + (size_t)(32 * c + srow) * K + k0 + scol),
              (char*)As + c * 4096 + wave * 1024);
      gload16((const void*)(Bb + (size_t)(32 * c + srow) * K + k0 + scol),
              (char*)Bs + c * 4096 + wave * 1024);
    }
    __syncthreads();
#pragma unroll
    for (int kk = 0; kk < 2; ++kk) {
      bf16x8 af[4], bfr[4];
#pragma unroll
      for (int mi = 0; mi < 4; ++mi) {
        int R = wr * 64 + mi * 16 + l15;
        af[mi] = *reinterpret_cast<const bf16x8*>(&As[R * 64 + (((kk * 4 + lg)) ^ l7) * 8]);
      }
#pragma unroll
      for (int ni = 0; ni < 4; ++ni) {
        int R = wc * 64 + ni * 16 + l15;
        bfr[ni] = *reinterpret_cast<const bf16x8*>(&Bs[R * 64 + (((kk * 4 + lg)) ^ l7) * 8]);
      }
      __builtin_amdgcn_s_setprio(1);
#pragma unroll
      for (int mi = 0; mi < 4; ++mi)
#pragma unroll
        for (int ni = 0; ni < 4; ++ni)
          acc[mi][ni] = MFMA16(af[mi], bfr[ni], acc[mi][ni]);
      __builtin_amdgcn_s_setprio(0);
    }
    __syncthreads();
  }

  if (EPI == 0) {
    const float av = alphaPtr[0];
    const int t = bn >> 3;
    if (t == 2) {
#pragma unroll
      for (int mi = 0; mi < 4; ++mi) {
        int row0 = bm * 128 + wr * 64 + mi * 16 + lg * 4;
        int bb = row0 >> 11, s = row0 & 2047;
#pragma unroll
        for (int ni = 0; ni < 4; ++ni) {
          int col = (bn & 7) * 128 + wc * 64 + ni * 16 + l15;
          int hh = col >> 6, dd = col & 63;
          ushort4 pk;
#pragma unroll
          for (int r = 0; r < 4; ++r) {
            float v = acc[mi][ni][r];
            float e = __expf(2.0f * v);
            v += av * 0.1f * (1.0f - 2.0f * __builtin_amdgcn_rcpf(e + 1.0f));
            ((unsigned short*)&pk)[r] = f2bf(v);
          }
          *reinterpret_cast<ushort4*>(VT + ((size_t)(bb * 16 + hh) * 64 + dd) * 2048 + s) = pk;
        }
      }
    } else {
#pragma unroll
      for (int mi = 0; mi < 4; ++mi)
#pragma unroll
        for (int ni = 0; ni < 4; ++ni)
#pragma unroll
          for (int r = 0; r < 4; ++r) {
            int row = wr * 64 + mi * 16 + lg * 4 + r;
            int col = wc * 64 + ni * 16 + l15;
            float v = acc[mi][ni][r];
            if (t == 0) {
              v += 0.1f * __sinf(v);
              v *= 0.18033688011112042f;  // C1: fold softmax scale*log2e into Q
            } else {
              v += 0.1f * __cosf(v);
            }
            smem[row * 136 + col] = f2bf(v);
          }
      __syncthreads();
      unsigned short* dst = (t == 0) ? Qf : Kf;
      const int c16 = tid & 15, rb = tid >> 4;
      const int ncol0 = (bn & 7) * 128;
#pragma unroll
      for (int i2 = 0; i2 < 8; ++i2) {
        int srow2 = rb + i2 * 16;
        uint4 val = *reinterpret_cast<const uint4*>(&smem[srow2 * 136 + c16 * 8]);
        *reinterpret_cast<uint4*>(dst + (size_t)(bm * 128 + srow2) * 1024 + ncol0 + c16 * 8) = val;
      }
    }
  } else {
#pragma unroll
    for (int ni = 0; ni < 4; ++ni) {
      int n = bn * 128 + wc * 64 + ni * 16 + l15;
#pragma unroll
      for (int mi = 0; mi < 4; ++mi) {
        int row = bm * 128 + wr * 64 + mi * 16 + lg * 4;
#pragma unroll
        for (int r = 0; r < 4; ++r)
          Out[(size_t)(row + r) * 1024 + n] = acc[mi][ni][r];
      }
    }
  }
}

// ---------------- flash attention: R14-exact (green @116us) ----------------
// 3-buffer counted-vmcnt pipeline: vmcnt(4) -> barrier -> issue t+2 -> compute.
__global__ __launch_bounds__(256)
__attribute__((amdgpu_waves_per_eu(4, 4)))
void k_attn(const unsigned short* __restrict__ Qf,
            const unsigned short* __restrict__ Kf,
            const unsigned short* __restrict__ VT,
            unsigned short* __restrict__ AO) {
  __shared__ __align__(16) unsigned short smem[3 * 8192];  // 3 x [Ks 64x64 | VT 64x64]
  const int tid = threadIdx.x;
  const int wave = tid >> 6, lane = tid & 63;
  const int l31 = lane & 31, hi = lane >> 5;
  const int f = (blockIdx.y << 4) | blockIdx.x;
  const int nf = ((f & 7) << 7) | (f >> 3);
  const int qb = nf & 15, bh = nf >> 4;
  const int b = bh >> 4, h = bh & 15;

  const unsigned short* Qb = Qf + ((size_t)b * 2048 + qb * 128 + wave * 32) * 1024 + h * 64;
  const unsigned short* Kb = Kf + (size_t)b * 2048 * 1024 + h * 64;
  const unsigned short* Vb = VT + (size_t)bh * 64 * 2048;

  bf16x8 qfr[4];
#pragma unroll
  for (int ds = 0; ds < 4; ++ds)
    qfr[ds] = *reinterpret_cast<const bf16x8*>(Qb + (size_t)l31 * 1024 + ds * 16 + hi * 8);
  asm volatile("s_waitcnt vmcnt(0)" ::: "memory");  // qfr resolved; vmcnt now ours alone

  float lsum = 0.f;
  f32x16 o0 = {}, o1 = {};

  const int krow0 = wave * 16 + (lane >> 3);
  const int ksrcc = ((lane & 7) ^ (lane >> 3)) << 3;
  const int kxor = l31 & 7;

  // ---- prologue: issue tiles 0 and 1 (8 loads outstanding) ----
#pragma unroll
  for (int tt = 0; tt < 2; ++tt) {
    char* Kd = (char*)(smem + tt * 8192) + wave * 2048;
    char* Vd = (char*)(smem + tt * 8192 + 4096) + wave * 2048;
    int kn = tt * 64;
    gload16((const void*)(Kb + (size_t)(kn + krow0) * 1024 + ksrcc), Kd);
    gload16((const void*)(Kb + (size_t)(kn + krow0 + 8) * 1024 + ksrcc), Kd + 1024);
    gload16((const void*)(Vb + (size_t)krow0 * 2048 + kn + ksrcc), Vd);
    gload16((const void*)(Vb + (size_t)(krow0 + 8) * 2048 + kn + ksrcc), Vd + 1024);
  }

  for (int t = 0; t < 32; ++t) {
    const unsigned short* KsC = smem + (t % 3) * 8192;
    const unsigned short* VTC = KsC + 4096;

    if (t < 31) asm volatile("s_waitcnt vmcnt(4)" ::: "memory");
    else        asm volatile("s_waitcnt vmcnt(0)" ::: "memory");
    __builtin_amdgcn_s_barrier();
    __builtin_amdgcn_sched_barrier(0);

    // ---- issue tile t+2 loads (buffer (t+2)%3: its t-1 readers are past) ----
    if (t < 30) {
      int kn = (t + 2) * 64;
      char* Kd = (char*)(smem + ((t + 2) % 3) * 8192) + wave * 2048;
      char* Vd = (char*)(smem + ((t + 2) % 3) * 8192 + 4096) + wave * 2048;
      gload16((const void*)(Kb + (size_t)(kn + krow0) * 1024 + ksrcc), Kd);
      gload16((const void*)(Kb + (size_t)(kn + krow0 + 8) * 1024 + ksrcc), Kd + 1024);
      gload16((const void*)(Vb + (size_t)krow0 * 2048 + kn + ksrcc), Vd);
      gload16((const void*)(Vb + (size_t)(krow0 + 8) * 2048 + kn + ksrcc), Vd + 1024);
    }

    // ---- QK^T swapped: S^T[key][q] = MFMA(A=K, B=Q') ----
    f32x16 s0 = {}, s1 = {};
    __builtin_amdgcn_s_setprio(1);
#pragma unroll
    for (int ds = 0; ds < 4; ++ds) {
      int ch = ((ds * 2 + hi) ^ kxor) * 8;
      bf16x8 kf0 = *reinterpret_cast<const bf16x8*>(&KsC[l31 * 64 + ch]);
      bf16x8 kf1 = *reinterpret_cast<const bf16x8*>(&KsC[(l31 + 32) * 64 + ch]);
      s0 = MFMA32(kf0, qfr[ds], s0);
      s1 = MFMA32(kf1, qfr[ds], s1);
    }
    __builtin_amdgcn_s_setprio(0);

    // ---- fixed-max softmax: p = 2^s (C1 pre-folded into Q); lane-local lsum ----
    float rs0 = 0.f, rs1 = 0.f, rs2 = 0.f, rs3 = 0.f;
#pragma unroll
    for (int r = 0; r < 16; r += 4) {
      float p0 = vexp2(s0[r]);     s0[r] = p0;     rs0 += p0;
      float p1 = vexp2(s0[r + 1]); s0[r + 1] = p1; rs1 += p1;
      float p2 = vexp2(s0[r + 2]); s0[r + 2] = p2; rs2 += p2;
      float p3 = vexp2(s0[r + 3]); s0[r + 3] = p3; rs3 += p3;
    }
#pragma unroll
    for (int r = 0; r < 16; r += 4) {
      float p0 = vexp2(s1[r]);     s1[r] = p0;     rs0 += p0;
      float p1 = vexp2(s1[r + 1]); s1[r + 1] = p1; rs1 += p1;
      float p2 = vexp2(s1[r + 2]); s1[r + 2] = p2; rs2 += p2;
      float p3 = vexp2(s1[r + 3]); s1[r + 3] = p3; rs3 += p3;
    }
    lsum += (rs0 + rs1) + (rs2 + rs3);

    // ---- PV swapped: out^T[d][q] += MFMA(A=V^T, B=P); pf built per-ks ----
    __builtin_amdgcn_s_setprio(1);
#pragma unroll
    for (int ks = 0; ks < 4; ++ks) {
      bf16x8 pf =
          (ks == 0) ? mk_pfrag(hi, s0[0], s0[1], s0[2], s0[3], s0[4], s0[5], s0[6], s0[7])
        : (ks == 1) ? mk_pfrag(hi, s0[8], s0[9], s0[10], s0[11], s0[12], s0[13], s0[14], s0[15])
        : (ks == 2) ? mk_pfrag(hi, s1[0], s1[1], s1[2], s1[3], s1[4], s1[5], s1[6], s1[7])
                    : mk_pfrag(hi, s1[8], s1[9], s1[10], s1[11], s1[12], s1[13], s1[14], s1[15]);
      int ch = ((ks * 2 + hi) ^ kxor) * 8;
      bf16x8 v0 = *reinterpret_cast<const bf16x8*>(&VTC[l31 * 64 + ch]);
      bf16x8 v1 = *reinterpret_cast<const bf16x8*>(&VTC[(l31 + 32) * 64 + ch]);
      o0 = MFMA32(v0, pf, o0);
      o1 = MFMA32(v1, pf, o1);
    }
    __builtin_amdgcn_s_setprio(0);
    // no trailing barrier: next iteration's vmcnt+barrier is the sync point
  }
  __syncthreads();  // all waves done with buffers before epilogue reuse

  // ---- epilogue: single cross-lane lsum reduce, normalize, store via LDS ----
  lsum += __shfl_xor(lsum, 32);
  const float inv = 1.0f / lsum;
  unsigned short* OL = smem + wave * 2304;
#pragma unroll
  for (int r = 0; r < 16; ++r) {
    int d0 = (r & 3) + 8 * (r >> 2) + 4 * hi;
    OL[l31 * 72 + d0] = f2bf(o0[r] * inv);
    OL[l31 * 72 + 32 + d0] = f2bf(o1[r] * inv);
  }
  __syncthreads();
#pragma unroll
  for (int p = 0; p < 4; ++p) {
    int u = tid + p * 256;
    int row = u >> 3, ch = u & 7;
    uint4 val = *reinterpret_cast<const uint4*>(&smem[(row >> 5) * 2304 + (row & 31) * 72 + ch * 8]);
    *reinterpret_cast<uint4*>(AO + ((size_t)b * 2048 + qb * 128 + row) * 1024 + h * 64 + ch * 8) = val;
  }
}

extern "C" void kernel_launch(void* const* d_in, const int* in_sizes, int n_in,
                              void* d_out, int out_size, void* d_ws, size_t ws_size,
                              hipStream_t stream) {
  const float* x = (const float*)d_in[0];
  const float* Wq = (const float*)d_in[1];
  const float* Wk = (const float*)d_in[2];
  const float* Wv = (const float*)d_in[3];
  const float* Wo = (const float*)d_in[4];
  const float* alpha = (const float*)d_in[5];
  float* out = (float*)d_out;

  char* ws = (char*)d_ws;
  unsigned short* xb  = (unsigned short*)(ws);
  unsigned short* WT3 = (unsigned short*)(ws + 16777216);
  unsigned short* WoT = (unsigned short*)(ws + 23068672);
  unsigned short* Qf  = (unsigned short*)(ws + 25165824);
  unsigned short* Kf  = (unsigned short*)(ws + 41943040);
  unsigned short* VTb = (unsigned short*)(ws + 58720256);  // [B][H][64][2048]
  unsigned short* AO  = (unsigned short*)(ws + 75497472);

  k_convx<<<dim3(8192), dim3(256), 0, stream>>>(x, xb);
  k_transw<<<dim3(32, 32), dim3(256), 0, stream>>>(Wq, WT3);
  k_transw<<<dim3(32, 32), dim3(256), 0, stream>>>(Wk, WT3 + 1024 * 1024);
  k_transw<<<dim3(32, 32), dim3(256), 0, stream>>>(Wv, WT3 + 2 * 1024 * 1024);
  k_transw<<<dim3(32, 32), dim3(256), 0, stream>>>(Wo, WoT);

  k_gemm<0><<<dim3(64, 24), dim3(256), 0, stream>>>(xb, WT3, 1024, Qf, Kf, VTb, alpha, nullptr);
  k_attn<<<dim3(16, 64), dim3(256), 0, stream>>>(Qf, Kf, VTb, AO);
  k_gemm<1><<<dim3(64, 8), dim3(256), 0, stream>>>(AO, WoT, 1024, nullptr, nullptr, nullptr, nullptr, out);
}

// Round 23
// 211.358 us; speedup vs baseline: 1.3428x; 1.0424x over previous
//
#include <hip/hip_runtime.h>

typedef __bf16 bf16x8 __attribute__((ext_vector_type(8)));
typedef float f32x4 __attribute__((ext_vector_type(4)));
typedef float f32x16 __attribute__((ext_vector_type(16)));

#define MFMA16(a,b,c) __builtin_amdgcn_mfma_f32_16x16x32_bf16(a,b,c,0,0,0)
#define MFMA32(a,b,c) __builtin_amdgcn_mfma_f32_32x32x16_bf16(a,b,c,0,0,0)

__device__ __forceinline__ unsigned short f2bf(float f) {
  unsigned int u = __float_as_uint(f);
  u = (u + 0x7FFFu + ((u >> 16) & 1u)) >> 16;
  return (unsigned short)u;
}

__device__ __forceinline__ void gload16(const void* g, void* l) {
  __builtin_amdgcn_global_load_lds(
      (const __attribute__((address_space(1))) void*)g,
      (__attribute__((address_space(3))) void*)l, 16, 0, 0);
}

__device__ __forceinline__ float vexp2(float x) {
  float r;
  asm("v_exp_f32 %0, %1" : "=v"(r) : "v"(x));
  return r;
}

// Build PV B-fragment (B[k=key][n=q], k = hi*8 + j) from the 8 fp32 P values
// this lane holds for one 16-key group (C/D order: key = (r&3) + 8*(r>>2) + 4*hi).
__device__ __forceinline__ bf16x8 mk_pfrag(int hi, float p0, float p1, float p2, float p3,
                                           float p4, float p5, float p6, float p7) {
  unsigned int a0, a1, b0, b1;
  asm("v_cvt_pk_bf16_f32 %0, %1, %2" : "=v"(a0) : "v"(p0), "v"(p1));
  asm("v_cvt_pk_bf16_f32 %0, %1, %2" : "=v"(a1) : "v"(p2), "v"(p3));
  asm("v_cvt_pk_bf16_f32 %0, %1, %2" : "=v"(b0) : "v"(p4), "v"(p5));
  asm("v_cvt_pk_bf16_f32 %0, %1, %2" : "=v"(b1) : "v"(p6), "v"(p7));
  unsigned int x = __shfl_xor(hi ? a0 : b0, 32);
  unsigned int y = __shfl_xor(hi ? a1 : b1, 32);
  uint4 w;
  w.x = hi ? x : a0;
  w.y = hi ? y : a1;
  w.z = hi ? b0 : x;
  w.w = hi ? b1 : y;
  return *reinterpret_cast<bf16x8*>(&w);
}

// ---------------- fused preprocessing: x->bf16 + 4x W transpose-convert ----------
// blocks [0,8192): convert x (fp32->bf16), 1024 elems/block
// blocks [8192,12288): transpose-convert W_z (z = (bid-8192)>>10) into bf16 [N][K]
__global__ __launch_bounds__(256) void k_prep(
    const float* __restrict__ x, unsigned short* __restrict__ xb,
    const float* __restrict__ Wq, const float* __restrict__ Wk,
    const float* __restrict__ Wv, const float* __restrict__ Wo,
    unsigned short* __restrict__ WT3, unsigned short* __restrict__ WoT) {
  __shared__ float t[32][33];
  const int bid = blockIdx.x;
  if (bid < 8192) {
    int i = (bid * 256 + threadIdx.x) * 4;
    float4 v = *reinterpret_cast<const float4*>(x + i);
    ushort4 o;
    o.x = f2bf(v.x); o.y = f2bf(v.y); o.z = f2bf(v.z); o.w = f2bf(v.w);
    *reinterpret_cast<ushort4*>(xb + i) = o;
  } else {
    const int r = bid - 8192;
    const int z = r >> 10;
    const int inner = r & 1023;
    const int bx = (inner & 31) * 32;   // n tile
    const int by = (inner >> 5) * 32;   // k tile
    const float* W = (z == 0) ? Wq : (z == 1) ? Wk : (z == 2) ? Wv : Wo;
    unsigned short* WT = (z == 3) ? WoT : WT3 + (size_t)z * 1024 * 1024;
    const int tx = threadIdx.x & 31;
    const int ty = threadIdx.x >> 5;
#pragma unroll
    for (int i = 0; i < 32; i += 8)
      t[ty + i][tx] = W[(size_t)(by + ty + i) * 1024 + bx + tx];
    __syncthreads();
#pragma unroll
    for (int i = 0; i < 32; i += 8)
      WT[(size_t)(bx + ty + i) * 1024 + by + tx] = f2bf(t[tx][ty + i]);
  }
}

// ---------------- GEMM 128x128, BK=64, swizzled LDS (R17 green) ----------------
template <int EPI>
__global__ __launch_bounds__(256) void k_gemm(
    const unsigned short* __restrict__ A, const unsigned short* __restrict__ BT, int K,
    unsigned short* __restrict__ Qf, unsigned short* __restrict__ Kf,
    unsigned short* __restrict__ VT, const float* __restrict__ alphaPtr,
    float* __restrict__ Out) {
  __shared__ __align__(16) unsigned short smem[128 * 136];
  unsigned short* As = smem;
  unsigned short* Bs = smem + 8192;
  const int tid = threadIdx.x;
  const int wave = tid >> 6, lane = tid & 63;
  const int l15 = lane & 15, lg = lane >> 4;
  const int l7 = l15 & 7;
  const int wr = wave >> 1, wc = wave & 1;
  const int bm = blockIdx.x, bn = blockIdx.y;

  f32x4 acc[4][4] = {};
  const unsigned short* Ab = A + (size_t)bm * 128 * K;
  const unsigned short* Bb = BT + (size_t)bn * 128 * K;

  const int srow = wave * 8 + (lane >> 3);
  const int scol = ((lane & 7) ^ (lane >> 3)) << 3;

  for (int k0 = 0; k0 < K; k0 += 64) {
#pragma unroll
    for (int c = 0; c < 4; ++c) {
      gload16((const void*)(Ab + (size_t)(32 * c + srow) * K + k0 + scol),
              (char*)As + c * 4096 + wave * 1024);
      gload16((const void*)(Bb + (size_t)(32 * c + srow) * K + k0 + scol),
              (char*)Bs + c * 4096 + wave * 1024);
    }
    __syncthreads();
#pragma unroll
    for (int kk = 0; kk < 2; ++kk) {
      bf16x8 af[4], bfr[4];
#pragma unroll
      for (int mi = 0; mi < 4; ++mi) {
        int R = wr * 64 + mi * 16 + l15;
        af[mi] = *reinterpret_cast<const bf16x8*>(&As[R * 64 + (((kk * 4 + lg)) ^ l7) * 8]);
      }
#pragma unroll
      for (int ni = 0; ni < 4; ++ni) {
        int R = wc * 64 + ni * 16 + l15;
        bfr[ni] = *reinterpret_cast<const bf16x8*>(&Bs[R * 64 + (((kk * 4 + lg)) ^ l7) * 8]);
      }
      __builtin_amdgcn_s_setprio(1);
#pragma unroll
      for (int mi = 0; mi < 4; ++mi)
#pragma unroll
        for (int ni = 0; ni < 4; ++ni)
          acc[mi][ni] = MFMA16(af[mi], bfr[ni], acc[mi][ni]);
      __builtin_amdgcn_s_setprio(0);
    }
    __syncthreads();
  }

  if (EPI == 0) {
    const float av = alphaPtr[0];
    const int t = bn >> 3;
    if (t == 2) {
#pragma unroll
      for (int mi = 0; mi < 4; ++mi) {
        int row0 = bm * 128 + wr * 64 + mi * 16 + lg * 4;
        int bb = row0 >> 11, s = row0 & 2047;
#pragma unroll
        for (int ni = 0; ni < 4; ++ni) {
          int col = (bn & 7) * 128 + wc * 64 + ni * 16 + l15;
          int hh = col >> 6, dd = col & 63;
          ushort4 pk;
#pragma unroll
          for (int r = 0; r < 4; ++r) {
            float v = acc[mi][ni][r];
            float e = __expf(2.0f * v);
            v += av * 0.1f * (1.0f - 2.0f * __builtin_amdgcn_rcpf(e + 1.0f));
            ((unsigned short*)&pk)[r] = f2bf(v);
          }
          *reinterpret_cast<ushort4*>(VT + ((size_t)(bb * 16 + hh) * 64 + dd) * 2048 + s) = pk;
        }
      }
    } else {
#pragma unroll
      for (int mi = 0; mi < 4; ++mi)
#pragma unroll
        for (int ni = 0; ni < 4; ++ni)
#pragma unroll
          for (int r = 0; r < 4; ++r) {
            int row = wr * 64 + mi * 16 + lg * 4 + r;
            int col = wc * 64 + ni * 16 + l15;
            float v = acc[mi][ni][r];
            if (t == 0) {
              v += 0.1f * __sinf(v);
              v *= 0.18033688011112042f;  // C1: fold softmax scale*log2e into Q
            } else {
              v += 0.1f * __cosf(v);
            }
            smem[row * 136 + col] = f2bf(v);
          }
      __syncthreads();
      unsigned short* dst = (t == 0) ? Qf : Kf;
      const int c16 = tid & 15, rb = tid >> 4;
      const int ncol0 = (bn & 7) * 128;
#pragma unroll
      for (int i2 = 0; i2 < 8; ++i2) {
        int srow2 = rb + i2 * 16;
        uint4 val = *reinterpret_cast<const uint4*>(&smem[srow2 * 136 + c16 * 8]);
        *reinterpret_cast<uint4*>(dst + (size_t)(bm * 128 + srow2) * 1024 + ncol0 + c16 * 8) = val;
      }
    }
  } else {
#pragma unroll
    for (int ni = 0; ni < 4; ++ni) {
      int n = bn * 128 + wc * 64 + ni * 16 + l15;
#pragma unroll
      for (int mi = 0; mi < 4; ++mi) {
        int row = bm * 128 + wr * 64 + mi * 16 + lg * 4;
#pragma unroll
        for (int r = 0; r < 4; ++r)
          Out[(size_t)(row + r) * 1024 + n] = acc[mi][ni][r];
      }
    }
  }
}

// ---------------- flash attention: R14-exact (green @116us) ----------------
// 3-buffer counted-vmcnt pipeline: vmcnt(4) -> barrier -> issue t+2 -> compute.
__global__ __launch_bounds__(256)
__attribute__((amdgpu_waves_per_eu(4, 4)))
void k_attn(const unsigned short* __restrict__ Qf,
            const unsigned short* __restrict__ Kf,
            const unsigned short* __restrict__ VT,
            unsigned short* __restrict__ AO) {
  __shared__ __align__(16) unsigned short smem[3 * 8192];  // 3 x [Ks 64x64 | VT 64x64]
  const int tid = threadIdx.x;
  const int wave = tid >> 6, lane = tid & 63;
  const int l31 = lane & 31, hi = lane >> 5;
  const int f = (blockIdx.y << 4) | blockIdx.x;
  const int nf = ((f & 7) << 7) | (f >> 3);
  const int qb = nf & 15, bh = nf >> 4;
  const int b = bh >> 4, h = bh & 15;

  const unsigned short* Qb = Qf + ((size_t)b * 2048 + qb * 128 + wave * 32) * 1024 + h * 64;
  const unsigned short* Kb = Kf + (size_t)b * 2048 * 1024 + h * 64;
  const unsigned short* Vb = VT + (size_t)bh * 64 * 2048;

  bf16x8 qfr[4];
#pragma unroll
  for (int ds = 0; ds < 4; ++ds)
    qfr[ds] = *reinterpret_cast<const bf16x8*>(Qb + (size_t)l31 * 1024 + ds * 16 + hi * 8);
  asm volatile("s_waitcnt vmcnt(0)" ::: "memory");  // qfr resolved; vmcnt now ours alone

  float lsum = 0.f;
  f32x16 o0 = {}, o1 = {};

  const int krow0 = wave * 16 + (lane >> 3);
  const int ksrcc = ((lane & 7) ^ (lane >> 3)) << 3;
  const int kxor = l31 & 7;

  // ---- prologue: issue tiles 0 and 1 (8 loads outstanding) ----
#pragma unroll
  for (int tt = 0; tt < 2; ++tt) {
    char* Kd = (char*)(smem + tt * 8192) + wave * 2048;
    char* Vd = (char*)(smem + tt * 8192 + 4096) + wave * 2048;
    int kn = tt * 64;
    gload16((const void*)(Kb + (size_t)(kn + krow0) * 1024 + ksrcc), Kd);
    gload16((const void*)(Kb + (size_t)(kn + krow0 + 8) * 1024 + ksrcc), Kd + 1024);
    gload16((const void*)(Vb + (size_t)krow0 * 2048 + kn + ksrcc), Vd);
    gload16((const void*)(Vb + (size_t)(krow0 + 8) * 2048 + kn + ksrcc), Vd + 1024);
  }

  for (int t = 0; t < 32; ++t) {
    const unsigned short* KsC = smem + (t % 3) * 8192;
    const unsigned short* VTC = KsC + 4096;

    if (t < 31) asm volatile("s_waitcnt vmcnt(4)" ::: "memory");
    else        asm volatile("s_waitcnt vmcnt(0)" ::: "memory");
    __builtin_amdgcn_s_barrier();
    __builtin_amdgcn_sched_barrier(0);

    // ---- issue tile t+2 loads (buffer (t+2)%3: its t-1 readers are past) ----
    if (t < 30) {
      int kn = (t + 2) * 64;
      char* Kd = (char*)(smem + ((t + 2) % 3) * 8192) + wave * 2048;
      char* Vd = (char*)(smem + ((t + 2) % 3) * 8192 + 4096) + wave * 2048;
      gload16((const void*)(Kb + (size_t)(kn + krow0) * 1024 + ksrcc), Kd);
      gload16((const void*)(Kb + (size_t)(kn + krow0 + 8) * 1024 + ksrcc), Kd + 1024);
      gload16((const void*)(Vb + (size_t)krow0 * 2048 + kn + ksrcc), Vd);
      gload16((const void*)(Vb + (size_t)(krow0 + 8) * 2048 + kn + ksrcc), Vd + 1024);
    }

    // ---- QK^T swapped: S^T[key][q] = MFMA(A=K, B=Q') ----
    f32x16 s0 = {}, s1 = {};
    __builtin_amdgcn_s_setprio(1);
#pragma unroll
    for (int ds = 0; ds < 4; ++ds) {
      int ch = ((ds * 2 + hi) ^ kxor) * 8;
      bf16x8 kf0 = *reinterpret_cast<const bf16x8*>(&KsC[l31 * 64 + ch]);
      bf16x8 kf1 = *reinterpret_cast<const bf16x8*>(&KsC[(l31 + 32) * 64 + ch]);
      s0 = MFMA32(kf0, qfr[ds], s0);
      s1 = MFMA32(kf1, qfr[ds], s1);
    }
    __builtin_amdgcn_s_setprio(0);

    // ---- fixed-max softmax: p = 2^s (C1 pre-folded into Q); lane-local lsum ----
    float rs0 = 0.f, rs1 = 0.f, rs2 = 0.f, rs3 = 0.f;
#pragma unroll
    for (int r = 0; r < 16; r += 4) {
      float p0 = vexp2(s0[r]);     s0[r] = p0;     rs0 += p0;
      float p1 = vexp2(s0[r + 1]); s0[r + 1] = p1; rs1 += p1;
      float p2 = vexp2(s0[r + 2]); s0[r + 2] = p2; rs2 += p2;
      float p3 = vexp2(s0[r + 3]); s0[r + 3] = p3; rs3 += p3;
    }
#pragma unroll
    for (int r = 0; r < 16; r += 4) {
      float p0 = vexp2(s1[r]);     s1[r] = p0;     rs0 += p0;
      float p1 = vexp2(s1[r + 1]); s1[r + 1] = p1; rs1 += p1;
      float p2 = vexp2(s1[r + 2]); s1[r + 2] = p2; rs2 += p2;
      float p3 = vexp2(s1[r + 3]); s1[r + 3] = p3; rs3 += p3;
    }
    lsum += (rs0 + rs1) + (rs2 + rs3);

    // ---- PV swapped: out^T[d][q] += MFMA(A=V^T, B=P); pf built per-ks ----
    __builtin_amdgcn_s_setprio(1);
#pragma unroll
    for (int ks = 0; ks < 4; ++ks) {
      bf16x8 pf =
          (ks == 0) ? mk_pfrag(hi, s0[0], s0[1], s0[2], s0[3], s0[4], s0[5], s0[6], s0[7])
        : (ks == 1) ? mk_pfrag(hi, s0[8], s0[9], s0[10], s0[11], s0[12], s0[13], s0[14], s0[15])
        : (ks == 2) ? mk_pfrag(hi, s1[0], s1[1], s1[2], s1[3], s1[4], s1[5], s1[6], s1[7])
                    : mk_pfrag(hi, s1[8], s1[9], s1[10], s1[11], s1[12], s1[13], s1[14], s1[15]);
      int ch = ((ks * 2 + hi) ^ kxor) * 8;
      bf16x8 v0 = *reinterpret_cast<const bf16x8*>(&VTC[l31 * 64 + ch]);
      bf16x8 v1 = *reinterpret_cast<const bf16x8*>(&VTC[(l31 + 32) * 64 + ch]);
      o0 = MFMA32(v0, pf, o0);
      o1 = MFMA32(v1, pf, o1);
    }
    __builtin_amdgcn_s_setprio(0);
    // no trailing barrier: next iteration's vmcnt+barrier is the sync point
  }
  __syncthreads();  // all waves done with buffers before epilogue reuse

  // ---- epilogue: single cross-lane lsum reduce, normalize, store via LDS ----
  lsum += __shfl_xor(lsum, 32);
  const float inv = 1.0f / lsum;
  unsigned short* OL = smem + wave * 2304;
#pragma unroll
  for (int r = 0; r < 16; ++r) {
    int d0 = (r & 3) + 8 * (r >> 2) + 4 * hi;
    OL[l31 * 72 + d0] = f2bf(o0[r] * inv);
    OL[l31 * 72 + 32 + d0] = f2bf(o1[r] * inv);
  }
  __syncthreads();
#pragma unroll
  for (int p = 0; p < 4; ++p) {
    int u = tid + p * 256;
    int row = u >> 3, ch = u & 7;
    uint4 val = *reinterpret_cast<const uint4*>(&smem[(row >> 5) * 2304 + (row & 31) * 72 + ch * 8]);
    *reinterpret_cast<uint4*>(AO + ((size_t)b * 2048 + qb * 128 + row) * 1024 + h * 64 + ch * 8) = val;
  }
}

extern "C" void kernel_launch(void* const* d_in, const int* in_sizes, int n_in,
                              void* d_out, int out_size, void* d_ws, size_t ws_size,
                              hipStream_t stream) {
  const float* x = (const float*)d_in[0];
  const float* Wq = (const float*)d_in[1];
  const float* Wk = (const float*)d_in[2];
  const float* Wv = (const float*)d_in[3];
  const float* Wo = (const float*)d_in[4];
  const float* alpha = (const float*)d_in[5];
  float* out = (float*)d_out;

  char* ws = (char*)d_ws;
  unsigned short* xb  = (unsigned short*)(ws);
  unsigned short* WT3 = (unsigned short*)(ws + 16777216);
  unsigned short* WoT = (unsigned short*)(ws + 23068672);
  unsigned short* Qf  = (unsigned short*)(ws + 25165824);
  unsigned short* Kf  = (unsigned short*)(ws + 41943040);
  unsigned short* VTb = (unsigned short*)(ws + 58720256);  // [B][H][64][2048]
  unsigned short* AO  = (unsigned short*)(ws + 75497472);

  k_prep<<<dim3(12288), dim3(256), 0, stream>>>(x, xb, Wq, Wk, Wv, Wo, WT3, WoT);
  k_gemm<0><<<dim3(64, 24), dim3(256), 0, stream>>>(xb, WT3, 1024, Qf, Kf, VTb, alpha, nullptr);
  k_attn<<<dim3(16, 64), dim3(256), 0, stream>>>(Qf, Kf, VTb, AO);
  k_gemm<1><<<dim3(64, 8), dim3(256), 0, stream>>>(AO, WoT, 1024, nullptr, nullptr, nullptr, nullptr, out);
}